// Round 3
// baseline (184.314 us; speedup 1.0000x reference)
//
#include <hip/hip_runtime.h>

#define PI2 6.28318530717958647692f

// ===========================================================================
// Kernel 1: per (b,t) plane.
// Phase 1: A2[w][kxi] = sum_{h<64} (X[h][w] + (-1)^kx X[h+64][w]) E1[kx][h]
// Phase 2: Xf[kxi][ky] = sum_{w<64} (A2[w] + (-1)^ky A2[w+64]) e^{-2pi i ky w/128}
// kxi 0..15 -> kx=kxi ; kxi 16..31 -> kx=kxi+96. Scale 1/16384.
// Xf layout: [plane][kxi][ky][ri] (1024 dwords/plane).
// ===========================================================================
__global__ __launch_bounds__(256) void k_fwd(const float* __restrict__ X,
                                             float* __restrict__ Xf) {
  __shared__ __attribute__((aligned(16))) float E1t[64 * 32 * 2];   // [h][kxi] f2, 16 KB
  __shared__ __attribute__((aligned(16))) float A2t[128 * 33 * 2];  // [w][kxi(+1)] f2, 33.8 KB
  const int plane = blockIdx.x;
  const int tid = threadIdx.x;
  const float* Xp = X + (size_t)plane * (128 * 128);

  // ---- twiddle table E1[h][kxi] = e^{-2pi i kx h/128} ----
  #pragma unroll
  for (int k = 0; k < 8; ++k) {
    int idx = tid + k * 256;          // 2048 entries
    int h = idx >> 5, kxi = idx & 31;
    int kx = kxi + ((kxi & 16) ? 96 : 0);
    float s_, c_;
    __sincosf(-PI2 * (float)((kx * h) & 127) * (1.f / 128.f), &s_, &c_);
    E1t[idx * 2] = c_; E1t[idx * 2 + 1] = s_;
  }
  __syncthreads();

  // ---- phase 1: thread = (w2 0..63, kxg 0..3); w = {2w2, 2w2+1}, kxi = 8kxg..+7
  {
    const int w2 = tid & 63;
    const int kxg = tid >> 6;
    float cr[8][2], ci[8][2];
    #pragma unroll
    for (int j = 0; j < 8; ++j) {
      cr[j][0] = cr[j][1] = 0.f; ci[j][0] = ci[j][1] = 0.f;
    }
    float2 xa = *(const float2*)&Xp[w2 * 2];
    float2 xb = *(const float2*)&Xp[64 * 128 + w2 * 2];
    for (int h = 0; h < 64; ++h) {
      float2 na = make_float2(0.f, 0.f), nb = make_float2(0.f, 0.f);
      if (h < 63) {
        na = *(const float2*)&Xp[(h + 1) * 128 + w2 * 2];
        nb = *(const float2*)&Xp[(h + 65) * 128 + w2 * 2];
      }
      float ue0 = xa.x + xb.x, ue1 = xa.y + xb.y;   // even kx
      float uo0 = xa.x - xb.x, uo1 = xa.y - xb.y;   // odd kx
      const float4* Er = (const float4*)&E1t[(h * 32 + kxg * 8) * 2];
      #pragma unroll
      for (int j2 = 0; j2 < 4; ++j2) {
        float4 e = Er[j2];            // (c_e, s_e, c_o, s_o) for kxi pair
        int je = 2 * j2, jo = 2 * j2 + 1;
        cr[je][0] = fmaf(ue0, e.x, cr[je][0]);
        ci[je][0] = fmaf(ue0, e.y, ci[je][0]);
        cr[je][1] = fmaf(ue1, e.x, cr[je][1]);
        ci[je][1] = fmaf(ue1, e.y, ci[je][1]);
        cr[jo][0] = fmaf(uo0, e.z, cr[jo][0]);
        ci[jo][0] = fmaf(uo0, e.w, ci[jo][0]);
        cr[jo][1] = fmaf(uo1, e.z, cr[jo][1]);
        ci[jo][1] = fmaf(uo1, e.w, ci[jo][1]);
      }
      xa = na; xb = nb;
    }
    #pragma unroll
    for (int u = 0; u < 2; ++u) {
      int w = 2 * w2 + u;
      #pragma unroll
      for (int j = 0; j < 8; ++j) {
        int f2i = w * 33 + 8 * kxg + j;
        A2t[f2i * 2] = cr[j][u]; A2t[f2i * 2 + 1] = ci[j][u];
      }
    }
  }
  __syncthreads();

  // ---- phase 2: thread = (kxi 0..31, t 0..7); ky = {t, t+8}; recurrence twiddle
  {
    const int kxi = tid >> 3;
    const int t = tid & 7;
    const float s = (t & 1) ? -1.f : 1.f;   // (-1)^ky
    float d0r, d0i, d1r, d1i;
    __sincosf(-PI2 * (float)t * (1.f / 128.f), &d0i, &d0r);
    __sincosf(-PI2 * (float)(t + 8) * (1.f / 128.f), &d1i, &d1r);
    float T0r = 1.f, T0i = 0.f, T1r = 1.f, T1i = 0.f;
    float r0 = 0.f, i0 = 0.f, r1 = 0.f, i1 = 0.f;
    #pragma unroll 4
    for (int w = 0; w < 64; ++w) {
      const float2 a = *(const float2*)&A2t[(w * 33 + kxi) * 2];
      const float2 b = *(const float2*)&A2t[((w + 64) * 33 + kxi) * 2];
      float ur = fmaf(s, b.x, a.x);
      float ui = fmaf(s, b.y, a.y);
      r0 = fmaf(ur, T0r, r0); r0 = fmaf(-ui, T0i, r0);
      i0 = fmaf(ur, T0i, i0); i0 = fmaf(ui, T0r, i0);
      r1 = fmaf(ur, T1r, r1); r1 = fmaf(-ui, T1i, r1);
      i1 = fmaf(ur, T1i, i1); i1 = fmaf(ui, T1r, i1);
      float n0r = T0r * d0r - T0i * d0i, n0i = T0r * d0i + T0i * d0r;
      float n1r = T1r * d1r - T1i * d1i, n1i = T1r * d1i + T1i * d1r;
      T0r = n0r; T0i = n0i; T1r = n1r; T1i = n1i;
    }
    const float sc = 1.f / 16384.f;
    float* base = Xf + (size_t)plane * 1024 + kxi * 32;
    *(float2*)&base[t * 2]       = make_float2(r0 * sc, i0 * sc);
    *(float2*)&base[(t + 8) * 2] = make_float2(r1 * sc, i1 * sc);
  }
}

// ===========================================================================
// Kernel 2: channel mix. block = (corner 2, x 16, cg 16), c-tile of 4.
// thread = (b 16, y 16). Y[b][c][kxi][ky][ri], same layout as Xf.
// ===========================================================================
__global__ __launch_bounds__(256) void k_mix(const float* __restrict__ Xf,
                                             const float* __restrict__ w0r,
                                             const float* __restrict__ w0i,
                                             const float* __restrict__ w1r,
                                             const float* __restrict__ w1i,
                                             float* __restrict__ Y) {
  __shared__ __attribute__((aligned(16))) float Wl[4 * 64 * 16 * 2]; // [c][t][y] f2
  const int bid = blockIdx.x;               // 0..511
  const int c2 = bid >> 8;
  const int x  = (bid >> 4) & 15;
  const int cg = bid & 15;
  const int c0 = cg * 4;
  const int kxi = c2 * 16 + x;
  const float* Wr_g = c2 ? w1r : w0r;
  const float* Wi_g = c2 ? w1i : w0i;
  const int tid = threadIdx.x;
  const int b = tid >> 4;
  const int y = tid & 15;

  // stage weights: 4096 complex elements, coalesced (y fastest, 64B runs)
  #pragma unroll
  for (int k = 0; k < 16; ++k) {
    int idx = tid + k * 256;                // 0..4095
    int y_ = idx & 15, t_ = (idx >> 4) & 63, c_ = idx >> 10;
    size_t ga = (((size_t)(c0 + c_) * 64 + t_) * 16 + x) * 16 + y_;
    float wr = Wr_g[ga], wi = Wi_g[ga];
    Wl[idx * 2] = wr; Wl[idx * 2 + 1] = wi;
  }
  __syncthreads();

  float aR[4] = {}, aI[4] = {};
  const float* xbase = Xf + ((size_t)b * 64) * 1024 + kxi * 32 + y * 2;
  for (int t8 = 0; t8 < 64; t8 += 8) {
    float2 xv[8];
    #pragma unroll
    for (int q = 0; q < 8; ++q)
      xv[q] = *(const float2*)&xbase[(size_t)(t8 + q) * 1024];
    #pragma unroll
    for (int q = 0; q < 8; ++q) {
      int t = t8 + q;
      #pragma unroll
      for (int cj = 0; cj < 4; ++cj) {
        const float2 wv = *(const float2*)&Wl[((cj * 64 + t) * 16 + y) * 2];
        aR[cj] = fmaf(xv[q].x, wv.x, aR[cj]);
        aR[cj] = fmaf(-xv[q].y, wv.y, aR[cj]);
        aI[cj] = fmaf(xv[q].x, wv.y, aI[cj]);
        aI[cj] = fmaf(xv[q].y, wv.x, aI[cj]);
      }
    }
  }
  #pragma unroll
  for (int cj = 0; cj < 4; ++cj) {
    size_t ya = ((size_t)(b * 64 + c0 + cj)) * 1024 + kxi * 32 + y * 2;
    *(float2*)&Y[ya] = make_float2(aR[cj], aI[cj]);
  }
}

// ===========================================================================
// Kernel 3: per (b,c) plane inverse.
// Phase A: Z[h][ky] = sum_kxi Y[kxi][ky] e^{+2pi i kx h/128}; store
//          (Mc,Ms)[h][ky] = (f*Zr, -f*Zi), f = (ky==0)?1:2.
// Phase B: out[h][w] = sum_ky Mc*cos(2pi ky w/128) + Ms*sin(...),
//          folded over w / w+64 via ky parity.
// ===========================================================================
__global__ __launch_bounds__(256) void k_inv(const float* __restrict__ Y,
                                             float* __restrict__ out) {
  __shared__ __attribute__((aligned(16))) float Yl[1024];
  __shared__ __attribute__((aligned(16))) float Ml[128 * 18 * 2];  // [h][ky(+2 pad)] f2
  const int plane = blockIdx.x;
  const int tid = threadIdx.x;
  {
    *(float4*)&Yl[tid * 4] = *(const float4*)&Y[(size_t)plane * 1024 + tid * 4];
  }
  __syncthreads();

  // ---- phase A: thread = (g 0..1 ky-half, h 0..127) ----
  {
    const int g = tid >> 7;
    const int h = tid & 127;
    float zr[8] = {}, zi[8] = {};
    float uw, uwi;   // U = e^{+2pi i h/128}
    __sincosf(PI2 * (float)h * (1.f / 128.f), &uwi, &uw);
    const float4* Yl4 = (const float4*)Yl;
    // run 1: kxi 0..15 (kx=0..15), T starts at 1
    float Tr = 1.f, Ti = 0.f;
    #pragma unroll 4
    for (int kxi = 0; kxi < 16; ++kxi) {
      #pragma unroll
      for (int q = 0; q < 4; ++q) {
        float4 p = Yl4[kxi * 8 + g * 4 + q];
        int m = 2 * q;
        zr[m]   = fmaf(p.x, Tr, zr[m]);   zr[m]   = fmaf(-p.y, Ti, zr[m]);
        zi[m]   = fmaf(p.x, Ti, zi[m]);   zi[m]   = fmaf(p.y, Tr, zi[m]);
        zr[m+1] = fmaf(p.z, Tr, zr[m+1]); zr[m+1] = fmaf(-p.w, Ti, zr[m+1]);
        zi[m+1] = fmaf(p.z, Ti, zi[m+1]); zi[m+1] = fmaf(p.w, Tr, zi[m+1]);
      }
      float nr = Tr * uw - Ti * uwi, ni = Tr * uwi + Ti * uw;
      Tr = nr; Ti = ni;
    }
    // run 2: kxi 16..31 (kx=112..127), T starts at e^{+2pi i 112 h/128}
    __sincosf(PI2 * (float)((112 * h) & 127) * (1.f / 128.f), &Ti, &Tr);
    #pragma unroll 4
    for (int kxi = 16; kxi < 32; ++kxi) {
      #pragma unroll
      for (int q = 0; q < 4; ++q) {
        float4 p = Yl4[kxi * 8 + g * 4 + q];
        int m = 2 * q;
        zr[m]   = fmaf(p.x, Tr, zr[m]);   zr[m]   = fmaf(-p.y, Ti, zr[m]);
        zi[m]   = fmaf(p.x, Ti, zi[m]);   zi[m]   = fmaf(p.y, Tr, zi[m]);
        zr[m+1] = fmaf(p.z, Tr, zr[m+1]); zr[m+1] = fmaf(-p.w, Ti, zr[m+1]);
        zi[m+1] = fmaf(p.z, Ti, zi[m+1]); zi[m+1] = fmaf(p.w, Tr, zi[m+1]);
      }
      float nr = Tr * uw - Ti * uwi, ni = Tr * uwi + Ti * uw;
      Tr = nr; Ti = ni;
    }
    #pragma unroll
    for (int m = 0; m < 8; ++m) {
      int ky = g * 8 + m;
      float f = (ky == 0) ? 1.f : 2.f;
      int f2i = h * 18 + ky;
      Ml[f2i * 2]     =  f * zr[m];
      Ml[f2i * 2 + 1] = -f * zi[m];
    }
  }
  __syncthreads();

  // ---- phase B: thread = (hq 0..3, w 0..63); 32 h each, outputs w and w+64 ----
  {
    const int hq = tid >> 6;
    const int w = tid & 63;
    float C[16], S[16];
    {
      float cw, sw;
      __sincosf(PI2 * (float)w * (1.f / 128.f), &sw, &cw);
      C[0] = 1.f; S[0] = 0.f;
      #pragma unroll
      for (int k = 1; k < 16; ++k) {
        C[k] = C[k - 1] * cw - S[k - 1] * sw;
        S[k] = C[k - 1] * sw + S[k - 1] * cw;
      }
    }
    float* op = out + (size_t)plane * (128 * 128);
    const float4* Ml4 = (const float4*)Ml;
    #pragma unroll 2
    for (int hj = 0; hj < 32; ++hj) {
      int h = hq * 32 + hj;
      float e = 0.f, o = 0.f;
      #pragma unroll
      for (int j2 = 0; j2 < 8; ++j2) {
        float4 m01 = Ml4[h * 9 + j2];   // (Mc,Ms) for ky=2j2, 2j2+1
        int k = 2 * j2;
        float t0 = m01.x * C[k] + m01.y * S[k];
        float t1 = m01.z * C[k + 1] + m01.w * S[k + 1];
        e += t0; o += t1;
      }
      op[h * 128 + w]      = e + o;
      op[h * 128 + w + 64] = e - o;
    }
  }
}

extern "C" void kernel_launch(void* const* d_in, const int* in_sizes, int n_in,
                              void* d_out, int out_size, void* d_ws, size_t ws_size,
                              hipStream_t stream) {
  const float* X   = (const float*)d_in[0];
  const float* w0r = (const float*)d_in[1];
  const float* w0i = (const float*)d_in[2];
  const float* w1r = (const float*)d_in[3];
  const float* w1i = (const float*)d_in[4];
  float* outp = (float*)d_out;
  float* Xf = (float*)d_ws;                  // 4 MB
  float* Yw = (float*)d_ws + (1u << 20);     // 4 MB
  k_fwd<<<1024, 256, 0, stream>>>(X, Xf);
  k_mix<<<512, 256, 0, stream>>>(Xf, w0r, w0i, w1r, w1i, Yw);
  k_inv<<<1024, 256, 0, stream>>>(Yw, outp);
}